// Round 2
// baseline (414.034 us; speedup 1.0000x reference)
//
#include <hip/hip_runtime.h>
#include <hip/hip_bf16.h>

// Problem: x[1][16][10][32][64][64], W[4][16][3][3][3][3], b[4]  (fp32 per reference)
// out[1][4][10][32][64][64] = softmax_over_channel(conv4d(x,W,pad=1)+b)
#define CIN  16
#define COUT 4
#define TT   10
#define ZZ   32
#define YY   64
#define XX   64

constexpr int SX_CI = TT * ZZ * YY * XX;  // 1310720 (also Cout stride of out)
constexpr int SX_T  = ZZ * YY * XX;       // 131072
constexpr int SX_Z  = YY * XX;            // 4096
constexpr int NW    = COUT * CIN * 81;    // 5184 weights
constexpr int FLAG_OFF = NW + COUT;       // int flag at wsf[5188]

// ---- dtype probe: decides fp32 vs bf16 from bit statistics of x ----
// fp32 data: even half-words are low mantissa bits -> uniform; ~45% have
// bf16-exponent-field > 140. bf16 N(0,1) data: ~0% do.
__global__ void probe_dtype(const unsigned short* __restrict__ xq,
                            int* __restrict__ flag) {
    __shared__ int cnt[256];
    const int tid = threadIdx.x;
    int c = 0;
    for (int k = 0; k < 64; ++k) {
        unsigned short u = xq[2 * (tid * 64 + k)];
        int e = (u >> 7) & 0xFF;
        if (e > 140) ++c;
    }
    cnt[tid] = c;
    __syncthreads();
    if (tid == 0) {
        int s = 0;
        for (int i = 0; i < 256; ++i) s += cnt[i];
        flag[0] = (s > 500) ? 1 : 0;   // 1 = fp32, 0 = bf16
    }
}

// ---- prep: weights+bias -> fp32 in workspace ----
__global__ void prep_weights(const void* __restrict__ W,
                             const void* __restrict__ b,
                             float* __restrict__ wsf,
                             const int* __restrict__ flag) {
    const int i = blockIdx.x * blockDim.x + threadIdx.x;
    const bool f32 = flag[0] != 0;
    if (i < NW)
        wsf[i] = f32 ? ((const float*)W)[i]
                     : __bfloat162float(((const __hip_bfloat16*)W)[i]);
    if (i < COUT)
        wsf[NW + i] = f32 ? ((const float*)b)[i]
                          : __bfloat162float(((const __hip_bfloat16*)b)[i]);
}

__device__ __forceinline__ float ldv(const float* p) { return *p; }
__device__ __forceinline__ float ldv(const __hip_bfloat16* p) { return __bfloat162float(*p); }
__device__ __forceinline__ void stv(float* p, float v) { *p = v; }
__device__ __forceinline__ void stv(__hip_bfloat16* p, float v) { *p = __float2bfloat16(v); }

// ---- main body: block (64,4); lanes = full x row, threadIdx.y = 4-y subtile.
// Each thread: 4 co x 4 y fp32 accumulators; halo via wave shuffles; weights
// via wave-uniform (scalar) fp32 loads from ws. ----
template <typename T>
__device__ __forceinline__ void conv_body(const T* __restrict__ x,
                                          const float* __restrict__ wsf,
                                          T* __restrict__ out) {
    const int lane = threadIdx.x;                        // x coordinate 0..63
    const int yo0  = blockIdx.x * 16 + threadIdx.y * 4;  // first output y
    const int z0   = blockIdx.y;
    const int t0   = blockIdx.z;

    float acc[COUT][4];
#pragma unroll
    for (int c = 0; c < COUT; ++c)
#pragma unroll
        for (int yl = 0; yl < 4; ++yl) acc[c][yl] = 0.f;

    for (int ci = 0; ci < CIN; ++ci) {
        for (int dt = 0; dt < 3; ++dt) {
            const int t_in = t0 + dt - 1;
            if ((unsigned)t_in >= TT) continue;   // zero padding: skip
            for (int dz = 0; dz < 3; ++dz) {
                const int z_in = z0 + dz - 1;
                if ((unsigned)z_in >= ZZ) continue;
                const T* __restrict__ bp =
                    x + (size_t)ci * SX_CI + (size_t)t_in * SX_T + (size_t)z_in * SX_Z;
                // weights for (ci,dt,dz): wsf[co*1296 + ci*81 + dt*27 + dz*9 + dy*3 + dx]
                const float* __restrict__ wb = wsf + (ci * 9 + dt * 3 + dz) * 9;
#pragma unroll
                for (int j = 0; j < 6; ++j) {     // input rows y_in = yo0-1 .. yo0+4
                    const int y_in = yo0 - 1 + j;
                    float vC = 0.f;
                    if ((unsigned)y_in < YY)      // wave-uniform guard
                        vC = ldv(bp + y_in * XX + lane);
                    float vL = __shfl_up(vC, 1, 64);
                    if (lane == 0) vL = 0.f;      // x = -1 pad
                    float vR = __shfl_down(vC, 1, 64);
                    if (lane == 63) vR = 0.f;     // x = 64 pad
#pragma unroll
                    for (int dy = 0; dy < 3; ++dy) {
                        const int yl = j - dy;    // local output row fed by this row
                        if (yl < 0 || yl > 3) continue;
#pragma unroll
                        for (int co = 0; co < COUT; ++co) {
                            const float* wp = wb + co * (CIN * 81) + dy * 3;
                            float a = acc[co][yl];
                            a = fmaf(vL, wp[0], a);   // dx=0 -> x_in = x-1
                            a = fmaf(vC, wp[1], a);   // dx=1 -> x_in = x
                            a = fmaf(vR, wp[2], a);   // dx=2 -> x_in = x+1
                            acc[co][yl] = a;
                        }
                    }
                }
            }
        }
    }

    const float b0 = wsf[NW + 0], b1 = wsf[NW + 1], b2 = wsf[NW + 2], b3 = wsf[NW + 3];
    const size_t obase = (size_t)t0 * SX_T + (size_t)z0 * SX_Z + lane;

#pragma unroll
    for (int yl = 0; yl < 4; ++yl) {
        float a0 = acc[0][yl] + b0;
        float a1 = acc[1][yl] + b1;
        float a2 = acc[2][yl] + b2;
        float a3 = acc[3][yl] + b3;
        const float m = fmaxf(fmaxf(a0, a1), fmaxf(a2, a3));
        const float e0 = __expf(a0 - m);
        const float e1 = __expf(a1 - m);
        const float e2 = __expf(a2 - m);
        const float e3 = __expf(a3 - m);
        const float inv = 1.f / (e0 + e1 + e2 + e3);
        T* __restrict__ op = out + obase + (size_t)(yo0 + yl) * XX;
        stv(op + 0 * (size_t)SX_CI, e0 * inv);
        stv(op + 1 * (size_t)SX_CI, e1 * inv);
        stv(op + 2 * (size_t)SX_CI, e2 * inv);
        stv(op + 3 * (size_t)SX_CI, e3 * inv);
    }
}

__global__ __launch_bounds__(256, 4) void conv4d_softmax(
        const void* __restrict__ x,
        const float* __restrict__ wsf,
        void* __restrict__ out,
        const int* __restrict__ flag) {
    if (flag[0]) {
        conv_body<float>((const float*)x, wsf, (float*)out);
    } else {
        conv_body<__hip_bfloat16>((const __hip_bfloat16*)x, wsf, (__hip_bfloat16*)out);
    }
}

extern "C" void kernel_launch(void* const* d_in, const int* in_sizes, int n_in,
                              void* d_out, int out_size, void* d_ws, size_t ws_size,
                              hipStream_t stream) {
    const void* x = d_in[0];
    const void* W = d_in[1];
    const void* b = d_in[2];
    float* wsf = (float*)d_ws;                   // 5188 floats + 1 int flag
    int* flag = (int*)(wsf + FLAG_OFF);

    probe_dtype<<<dim3(1), dim3(256), 0, stream>>>((const unsigned short*)x, flag);
    prep_weights<<<dim3((NW + 255) / 256), dim3(256), 0, stream>>>(W, b, wsf, flag);

    dim3 grid(YY / 16, ZZ, TT);   // (4, 32, 10) = 1280 blocks
    dim3 block(64, 4, 1);         // 256 threads: full x-row per wave
    conv4d_softmax<<<grid, block, 0, stream>>>(x, wsf, d_out, flag);
}

// Round 3
// 386.769 us; speedup vs baseline: 1.0705x; 1.0705x over previous
//
#include <hip/hip_runtime.h>

// Problem (all fp32): x[1][16][10][32][64][64], W[4][16][3][3][3][3], b[4]
// out[1][4][10][32][64][64] = softmax_over_channel(conv4d(x,W,pad=1)+b)
// R2 proved inputs/outputs are fp32 (dtype probe selected fp32; bf16 path => NaN).
#define CIN  16
#define COUT 4
#define TT   10
#define ZZ   32
#define YY   64
#define XX   64

constexpr int SX_CI = TT * ZZ * YY * XX;  // 1310720 (also Cout stride of out)
constexpr int SX_T  = ZZ * YY * XX;       // 131072
constexpr int SX_Z  = YY * XX;            // 4096
constexpr int WCO   = CIN * 81;           // 1296: co stride in W

// Block (64,4): one wave per threadIdx.y. Lane = (yl = lane>>4, xg = lane&15).
// Thread computes output row y = blk.x*16 + tidy*4 + yl, x = xg*4 .. xg*4+3,
// all 4 Cout -> 16 fp32 accumulators. Wave's 64 lanes read 4 consecutive
// y-rows as float4 => 1024B fully-coalesced per row-load group.
// Padding is branchless: clamped addresses + cndmask zeroing, so the 27-row
// (dt,dz,e) body fully unrolls and loads pipeline across ci iterations.
__global__ __launch_bounds__(256, 4) void conv4d_softmax(
        const float* __restrict__ x,
        const float* __restrict__ W,
        const float* __restrict__ b,
        float* __restrict__ out) {
    const int lane = threadIdx.x;            // 0..63
    const int xg   = lane & 15;              // float4 group; x0 = xg*4
    const int yl   = lane >> 4;              // 0..3
    const int y    = blockIdx.x * 16 + threadIdx.y * 4 + yl;  // output y
    const int z0   = blockIdx.y;
    const int t0   = blockIdx.z;
    const int x0   = xg * 4;

    float acc[COUT][4];
#pragma unroll
    for (int c = 0; c < COUT; ++c)
#pragma unroll
        for (int xi = 0; xi < 4; ++xi) acc[c][xi] = 0.f;

    for (int ci = 0; ci < CIN; ++ci) {
        const float* __restrict__ xc = x + (size_t)ci * SX_CI;
        const float* __restrict__ wc = W + ci * 81;
#pragma unroll
        for (int dt = 0; dt < 3; ++dt) {
            const int  t_in = t0 + dt - 1;
            const int  t_c  = min(max(t_in, 0), TT - 1);
            const bool tv   = (unsigned)t_in < TT;
#pragma unroll
            for (int dz = 0; dz < 3; ++dz) {
                const int  z_in = z0 + dz - 1;
                const int  z_c  = min(max(z_in, 0), ZZ - 1);
                const bool tzv  = tv && ((unsigned)z_in < ZZ);
                const float* __restrict__ plane =
                    xc + (size_t)t_c * SX_T + (size_t)z_c * SX_Z;
                const float* __restrict__ wb = wc + (dt * 3 + dz) * 9;
#pragma unroll
                for (int e = 0; e < 3; ++e) {        // input row y+e-1, dy = e
                    const int  y_in = y + e - 1;
                    const int  y_c  = min(max(y_in, 0), YY - 1);
                    const bool v    = tzv && ((unsigned)y_in < YY);
                    // clamped address is always in-bounds; zero via selects
                    float4 f = *(const float4*)(plane + y_c * XX + x0);
                    f.x = v ? f.x : 0.f;
                    f.y = v ? f.y : 0.f;
                    f.z = v ? f.z : 0.f;
                    f.w = v ? f.w : 0.f;
                    // x halo: left = prev group's .w, right = next group's .x
                    float hl = __shfl(f.w, (lane - 1) & 63, 64);
                    hl = (xg == 0) ? 0.f : hl;       // x = -1 pad
                    float hr = __shfl(f.x, (lane + 1) & 63, 64);
                    hr = (xg == 15) ? 0.f : hr;      // x = 64 pad
                    const float win[6] = {hl, f.x, f.y, f.z, f.w, hr};
#pragma unroll
                    for (int co = 0; co < COUT; ++co) {
                        const float* __restrict__ wp = wb + co * WCO + e * 3;
                        const float w0 = wp[0], w1 = wp[1], w2 = wp[2];
#pragma unroll
                        for (int xi = 0; xi < 4; ++xi) {
                            float a = acc[co][xi];
                            a = fmaf(win[xi + 0], w0, a);
                            a = fmaf(win[xi + 1], w1, a);
                            a = fmaf(win[xi + 2], w2, a);
                            acc[co][xi] = a;
                        }
                    }
                }
            }
        }
    }

    const float b0 = b[0], b1 = b[1], b2 = b[2], b3 = b[3];
    float4 r[COUT];
#pragma unroll
    for (int xi = 0; xi < 4; ++xi) {
        const float a0 = acc[0][xi] + b0;
        const float a1 = acc[1][xi] + b1;
        const float a2 = acc[2][xi] + b2;
        const float a3 = acc[3][xi] + b3;
        const float m  = fmaxf(fmaxf(a0, a1), fmaxf(a2, a3));
        const float e0 = __expf(a0 - m);
        const float e1 = __expf(a1 - m);
        const float e2 = __expf(a2 - m);
        const float e3 = __expf(a3 - m);
        const float inv = 1.f / (e0 + e1 + e2 + e3);
        ((float*)&r[0])[xi] = e0 * inv;
        ((float*)&r[1])[xi] = e1 * inv;
        ((float*)&r[2])[xi] = e2 * inv;
        ((float*)&r[3])[xi] = e3 * inv;
    }
    float* __restrict__ op =
        out + (size_t)t0 * SX_T + (size_t)z0 * SX_Z + (size_t)y * XX + x0;
#pragma unroll
    for (int co = 0; co < COUT; ++co)
        *(float4*)(op + (size_t)co * SX_CI) = r[co];
}

extern "C" void kernel_launch(void* const* d_in, const int* in_sizes, int n_in,
                              void* d_out, int out_size, void* d_ws, size_t ws_size,
                              hipStream_t stream) {
    const float* x = (const float*)d_in[0];
    const float* W = (const float*)d_in[1];
    const float* b = (const float*)d_in[2];
    float* out = (float*)d_out;

    dim3 grid(YY / 16, ZZ, TT);   // (4, 32, 10) = 1280 blocks, 5/CU
    dim3 block(64, 4, 1);         // 4 waves: each wave = 4 y-rows x 64 x
    conv4d_softmax<<<grid, block, 0, stream>>>(x, W, b, out);
}

// Round 4
// 228.793 us; speedup vs baseline: 1.8096x; 1.6905x over previous
//
#include <hip/hip_runtime.h>
#include <hip/hip_bf16.h>

// Problem (fp32 in/out): x[1][16][10][32][64][64], W[4][16][3][3][3][3], b[4]
// out[1][4][10][32][64][64] = softmax_over_channel(conv4d(x,W,pad=1)+b)
//
// MFMA path: D[m=x-pos][n=(dx,co)] += sum over K=(offset,ci) of
//   x_t[t+dt-1][z+dz-1][y+dy-1][x0+m][ci] * W[co][ci][dt][dz][dy][dx]
// 14 x mfma_f32_16x16x32_bf16 per 16-x tile = full 1296-deep reduction.
// dx combined per-row via LDS gather; padding via zero-region addr redirect.
#define CIN  16
#define COUT 4
#define TT   10
#define ZZ   32
#define YY   64
#define XX   64

constexpr int SX_CI = TT * ZZ * YY * XX;  // 1310720
constexpr int SX_T  = ZZ * YY * XX;       // 131072
constexpr int SX_Z  = YY * XX;            // 4096
constexpr int WCO   = CIN * 81;           // 1296

// x_t byte strides (bf16, ci innermost: [t][z][y][x][ci])
constexpr int XT_TB = ZZ * YY * XX * CIN * 2;  // 4194304
constexpr int XT_ZB = YY * XX * CIN * 2;       // 131072
constexpr int XT_YB = XX * CIN * 2;            // 2048
constexpr size_t XT_BYTES = (size_t)TT * XT_TB;          // 41,943,040
constexpr size_t TABLE_OFF = XT_BYTES;                   // B-frag table: 14*64*16 B
constexpr size_t ZERO_OFF  = TABLE_OFF + 14 * 1024;      // 2560 B zeroed region
constexpr size_t WS_NEED   = ZERO_OFF + 2560;

typedef short  short8 __attribute__((ext_vector_type(8)));
typedef float  f32x4  __attribute__((ext_vector_type(4)));

__device__ __forceinline__ unsigned short f2bf(float f) {
    union { __hip_bfloat16 h; unsigned short u; } c;
    c.h = __float2bfloat16(f);
    return c.u;
}

// ---- transpose: x (fp32, ci outer) -> x_t (bf16, ci inner). One (t,z,y) row
// per 128-thread block. ----
__global__ void transpose_x(const float* __restrict__ x, char* __restrict__ ws) {
    __shared__ float lds[CIN * XX];   // [ci][x]
    const int y = blockIdx.x, z = blockIdx.y, t = blockIdx.z;
    const int tid = threadIdx.x;
    const size_t base = (size_t)t * SX_T + (size_t)z * SX_Z + (size_t)y * XX;
#pragma unroll
    for (int k = 0; k < 8; ++k) {
        const int i = tid + k * 128;          // i = c*64 + xx
        const int c = i >> 6, xx = i & 63;
        lds[i] = x[(size_t)c * SX_CI + base + xx];
    }
    __syncthreads();
    const int p = tid >> 1, h = tid & 1;      // point, ci-half
    unsigned int d[4];
#pragma unroll
    for (int j = 0; j < 4; ++j) {
        const unsigned short lo = f2bf(lds[(h * 8 + 2 * j + 0) * XX + p]);
        const unsigned short hi = f2bf(lds[(h * 8 + 2 * j + 1) * XX + p]);
        d[j] = (unsigned int)lo | ((unsigned int)hi << 16);
    }
    char* dst = ws + ((((size_t)t * ZZ + z) * YY + y) * XX + p) * 32 + h * 16;
    *(uint4*)dst = make_uint4(d[0], d[1], d[2], d[3]);
}

// ---- prep: per-lane B fragments (weights) + zero region ----
// Pair p, lane L: n=L&15 -> (co=n&3, dx=n>>2), quad=L>>4 -> (sel=quad>>1,
// ci_lo=(quad&1)*8); k=quad*8+j -> offset idx=2p+sel, ci=ci_lo+j.
__global__ void prep_B(const float* __restrict__ W, char* __restrict__ ws) {
    const int g = blockIdx.x * 128 + threadIdx.x;
    if (g < 14 * 64) {
        const int p = g >> 6, L = g & 63;
        const int q = L >> 4, n = L & 15;
        const int co = n & 3, dx = n >> 2;
        const int sel = q >> 1, cilo = (q & 1) * 8;
        const int idx = 2 * p + sel;          // (dt,dz,dy) index, 0..26
        unsigned int d[4];
#pragma unroll
        for (int j = 0; j < 4; ++j) {
            unsigned short u[2];
#pragma unroll
            for (int s = 0; s < 2; ++s) {
                float val = 0.f;
                if (dx < 3 && idx < 27) {
                    const int dt = idx / 9, dz = (idx / 3) % 3, dy = idx % 3;
                    const int ci = cilo + 2 * j + s;
                    val = W[(co * CIN + ci) * 81 + dt * 27 + dz * 9 + dy * 3 + dx];
                }
                u[s] = f2bf(val);
            }
            d[j] = (unsigned int)u[0] | ((unsigned int)u[1] << 16);
        }
        *(uint4*)(ws + TABLE_OFF + (size_t)p * 1024 + (size_t)L * 16) =
            make_uint4(d[0], d[1], d[2], d[3]);
    } else if (g < 14 * 64 + 640) {
        ((unsigned int*)(ws + ZERO_OFF))[g - 14 * 64] = 0u;
    }
}

// ---- main: block (64,4); wave w owns 4 y-rows of (t0,z0,y-quarter). Per row:
// 4 x-tiles x 14 MFMAs, D -> wave-private LDS, dx-gather + softmax + store. ----
#define LROW 21   // LDS row stride (dwords); odd => conflict-free epilogue reads
__global__ __launch_bounds__(256, 3) void conv_mfma(
        const char* __restrict__ ws,
        const float* __restrict__ bias,
        float* __restrict__ out) {
    __shared__ float smem[4 * 66 * LROW];
    const int lane = threadIdx.x;
    const int wid  = __builtin_amdgcn_readfirstlane(threadIdx.y);
    const int yq = blockIdx.x, z0 = blockIdx.y, t0 = blockIdx.z;

    // B fragments: 14 x 8 bf16 held in VGPRs for the whole kernel
    short8 Bf[14];
#pragma unroll
    for (int p = 0; p < 14; ++p)
        Bf[p] = *(const short8*)(ws + TABLE_OFF + p * 1024 + lane * 16);

    // scalar per-block plane offsets for the 27 (dt,dz,dy) slots
    int  pb[27];
    bool tzv[27];
#pragma unroll
    for (int idx = 0; idx < 27; ++idx) {
        const int dt = idx / 9, dz = (idx / 3) % 3;
        const int t_in = t0 + dt - 1, z_in = z0 + dz - 1;
        const int tc = min(max(t_in, 0), TT - 1);
        const int zc = min(max(z_in, 0), ZZ - 1);
        tzv[idx] = ((unsigned)t_in < TT) && ((unsigned)z_in < ZZ);
        pb[idx]  = tc * XT_TB + zc * XT_ZB;
    }
    // per-lane constant A voffset: m*32 + (quad&1)*16
    const int voffbase = (lane & 15) * 32 + ((lane >> 4) & 1) * 16;
    float* swave = smem + wid * (66 * LROW);
    if (lane < LROW) {                 // zero pad rows x_in=-1 and x_in=64
        swave[lane] = 0.f;
        swave[65 * LROW + lane] = 0.f;
    }

    const float bi0 = bias[0], bi1 = bias[1], bi2 = bias[2], bi3 = bias[3];

#pragma unroll 1
    for (int r = 0; r < 4; ++r) {
        const int y = yq * 16 + wid * 4 + r;
        // scalar row offsets (28 slots; slot 27 = K-pad -> zero region)
        int roff[28];
#pragma unroll
        for (int idx = 0; idx < 27; ++idx) {
            const int dy = idx % 3;
            const int y_in = y + dy - 1;
            const int yc = min(max(y_in, 0), YY - 1);
            const bool v = tzv[idx] && ((unsigned)y_in < YY);
            roff[idx] = v ? (pb[idx] + yc * XT_YB) : (int)ZERO_OFF;
        }
        roff[27] = (int)ZERO_OFF;

#pragma unroll 1
        for (int xt = 0; xt < 4; ++xt) {
            f32x4 acc = {0.f, 0.f, 0.f, 0.f};
            const int vbase = voffbase + xt * 512;   // + x0*32
#pragma unroll
            for (int p = 0; p < 14; ++p) {
                const int rel = (lane & 32) ? roff[2 * p + 1] : roff[2 * p];
                const short8 a = *(const short8*)(ws + (size_t)(unsigned)(rel + vbase));
                acc = __builtin_amdgcn_mfma_f32_16x16x32_bf16(a, Bf[p], acc, 0, 0, 0);
            }
            // D -> LDS: row = x_in+1 = xt*16 + quad*4 + reg + 1, col = n
            const int colw = lane & 15;
            const int rowb = xt * 16 + (lane >> 4) * 4 + 1;
#pragma unroll
            for (int reg = 0; reg < 4; ++reg)
                swave[(rowb + reg) * LROW + colw] = acc[reg];
        }
        // epilogue: lane = x_out; gather 3 dx x 4 co, softmax, store
        float lg0 = bi0, lg1 = bi1, lg2 = bi2, lg3 = bi3;
#pragma unroll
        for (int dx = 0; dx < 3; ++dx) {
            const float* sp = swave + (lane + dx) * LROW + dx * 4;
            lg0 += sp[0]; lg1 += sp[1]; lg2 += sp[2]; lg3 += sp[3];
        }
        const float m  = fmaxf(fmaxf(lg0, lg1), fmaxf(lg2, lg3));
        const float e0 = __expf(lg0 - m);
        const float e1 = __expf(lg1 - m);
        const float e2 = __expf(lg2 - m);
        const float e3 = __expf(lg3 - m);
        const float inv = 1.f / (e0 + e1 + e2 + e3);
        float* op = out + (size_t)t0 * SX_T + (size_t)z0 * SX_Z + (size_t)y * XX + lane;
        op[0 * (size_t)SX_CI] = e0 * inv;
        op[1 * (size_t)SX_CI] = e1 * inv;
        op[2 * (size_t)SX_CI] = e2 * inv;
        op[3 * (size_t)SX_CI] = e3 * inv;
    }
}

// ================= fallback (R3 vector kernel) if ws too small =================
__global__ __launch_bounds__(256, 4) void conv4d_softmax_vec(
        const float* __restrict__ x, const float* __restrict__ W,
        const float* __restrict__ b, float* __restrict__ out) {
    const int lane = threadIdx.x;
    const int xg = lane & 15, yl = lane >> 4;
    const int y = blockIdx.x * 16 + threadIdx.y * 4 + yl;
    const int z0 = blockIdx.y, t0 = blockIdx.z, x0 = xg * 4;
    float acc[COUT][4];
#pragma unroll
    for (int c = 0; c < COUT; ++c)
#pragma unroll
        for (int xi = 0; xi < 4; ++xi) acc[c][xi] = 0.f;
    for (int ci = 0; ci < CIN; ++ci) {
        const float* xc = x + (size_t)ci * SX_CI;
        const float* wc = W + ci * 81;
#pragma unroll
        for (int dt = 0; dt < 3; ++dt) {
            const int t_in = t0 + dt - 1;
            const int t_c = min(max(t_in, 0), TT - 1);
            const bool tv = (unsigned)t_in < TT;
#pragma unroll
            for (int dz = 0; dz < 3; ++dz) {
                const int z_in = z0 + dz - 1;
                const int z_c = min(max(z_in, 0), ZZ - 1);
                const bool tzvv = tv && ((unsigned)z_in < ZZ);
                const float* plane = xc + (size_t)t_c * SX_T + (size_t)z_c * SX_Z;
                const float* wb = wc + (dt * 3 + dz) * 9;
#pragma unroll
                for (int e = 0; e < 3; ++e) {
                    const int y_in = y + e - 1;
                    const int y_c = min(max(y_in, 0), YY - 1);
                    const bool v = tzvv && ((unsigned)y_in < YY);
                    float4 f = *(const float4*)(plane + y_c * XX + x0);
                    f.x = v ? f.x : 0.f; f.y = v ? f.y : 0.f;
                    f.z = v ? f.z : 0.f; f.w = v ? f.w : 0.f;
                    float hl = __shfl(f.w, (lane - 1) & 63, 64);
                    hl = (xg == 0) ? 0.f : hl;
                    float hr = __shfl(f.x, (lane + 1) & 63, 64);
                    hr = (xg == 15) ? 0.f : hr;
                    const float win[6] = {hl, f.x, f.y, f.z, f.w, hr};
#pragma unroll
                    for (int co = 0; co < COUT; ++co) {
                        const float* wp = wb + co * WCO + e * 3;
                        const float w0 = wp[0], w1 = wp[1], w2 = wp[2];
#pragma unroll
                        for (int xi = 0; xi < 4; ++xi) {
                            float a = acc[co][xi];
                            a = fmaf(win[xi], w0, a);
                            a = fmaf(win[xi + 1], w1, a);
                            a = fmaf(win[xi + 2], w2, a);
                            acc[co][xi] = a;
                        }
                    }
                }
            }
        }
    }
    const float b0 = b[0], b1 = b[1], b2 = b[2], b3 = b[3];
    float4 rr[COUT];
#pragma unroll
    for (int xi = 0; xi < 4; ++xi) {
        const float a0 = acc[0][xi] + b0, a1 = acc[1][xi] + b1;
        const float a2 = acc[2][xi] + b2, a3 = acc[3][xi] + b3;
        const float m = fmaxf(fmaxf(a0, a1), fmaxf(a2, a3));
        const float e0 = __expf(a0 - m), e1 = __expf(a1 - m);
        const float e2 = __expf(a2 - m), e3 = __expf(a3 - m);
        const float inv = 1.f / (e0 + e1 + e2 + e3);
        ((float*)&rr[0])[xi] = e0 * inv; ((float*)&rr[1])[xi] = e1 * inv;
        ((float*)&rr[2])[xi] = e2 * inv; ((float*)&rr[3])[xi] = e3 * inv;
    }
    float* op = out + (size_t)t0 * SX_T + (size_t)z0 * SX_Z + (size_t)y * XX + x0;
#pragma unroll
    for (int co = 0; co < COUT; ++co)
        *(float4*)(op + (size_t)co * SX_CI) = rr[co];
}

extern "C" void kernel_launch(void* const* d_in, const int* in_sizes, int n_in,
                              void* d_out, int out_size, void* d_ws, size_t ws_size,
                              hipStream_t stream) {
    const float* x = (const float*)d_in[0];
    const float* W = (const float*)d_in[1];
    const float* b = (const float*)d_in[2];
    float* out = (float*)d_out;

    if (ws_size >= WS_NEED) {
        char* ws = (char*)d_ws;
        transpose_x<<<dim3(YY, ZZ, TT), dim3(128), 0, stream>>>(x, ws);
        prep_B<<<dim3(12), dim3(128), 0, stream>>>(W, ws);
        conv_mfma<<<dim3(4, ZZ, TT), dim3(64, 4), 0, stream>>>(ws, b, out);
    } else {
        conv4d_softmax_vec<<<dim3(4, ZZ, TT), dim3(64, 4), 0, stream>>>(x, W, b, out);
    }
}